// Round 6
// baseline (90.201 us; speedup 1.0000x reference)
//
#include <hip/hip_runtime.h>

#define CUBIC_A (-0.75f)

typedef float f4nt __attribute__((ext_vector_type(4)));

__device__ __forceinline__ void nt_store4(float4* p, float4 v) {
    f4nt t;
    t.x = v.x; t.y = v.y; t.z = v.z; t.w = v.w;
    __builtin_nontemporal_store(t, (f4nt*)p);
}

__device__ __forceinline__ float cubic_w(float d) {
    float ad = fabsf(d);
    if (ad <= 1.0f) return ((CUBIC_A + 2.0f) * ad - (CUBIC_A + 3.0f)) * ad * ad + 1.0f;
    if (ad < 2.0f)  return CUBIC_A * (((ad - 5.0f) * ad + 8.0f) * ad - 4.0f);
    return 0.0f;
}

__device__ __forceinline__ float4 bicubic_pe(const float4* __restrict__ wgt,
                                             int px, int out_hw, int d4) {
    const int i = px / out_hw;
    const int j = px % out_hw;
    const float scale = 64.0f / (float)out_hw;
    const float si = ((float)i + 0.5f) * scale - 0.5f;
    const float sj = ((float)j + 0.5f) * scale - 0.5f;
    const int i0 = (int)floorf(si);
    const int j0 = (int)floorf(sj);
    int ih[4], iw[4];
    float wh[4], ww[4];
#pragma unroll
    for (int a = 0; a < 4; ++a) {
        int tp = i0 - 1 + a;
        wh[a] = cubic_w(si - (float)tp);
        ih[a] = min(63, max(0, tp));
        tp = j0 - 1 + a;
        ww[a] = cubic_w(sj - (float)tp);
        iw[a] = min(63, max(0, tp));
    }
    float ax = 0.f, ay = 0.f, az = 0.f, aw = 0.f;
#pragma unroll
    for (int a = 0; a < 4; ++a) {
        float rx = 0.f, ry = 0.f, rz = 0.f, rw = 0.f;
#pragma unroll
        for (int c = 0; c < 4; ++c) {
            const float4 v = wgt[(size_t)(ih[a] * 64 + iw[c]) * 256 + d4];
            rx = fmaf(ww[c], v.x, rx);
            ry = fmaf(ww[c], v.y, ry);
            rz = fmaf(ww[c], v.z, rz);
            rw = fmaf(ww[c], v.w, rw);
        }
        ax = fmaf(wh[a], rx, ax);
        ay = fmaf(wh[a], ry, ay);
        az = fmaf(wh[a], rz, az);
        aw = fmaf(wh[a], rw, aw);
    }
    return make_float4(ax, ay, az, aw);
}

// Kernel A: materialize interpolated pe rows for the two interp grids into ws.
// ws rows (float4[256]): [0,1024) = 32x32 pixels, [1024,3328) = 48x48 pixels.
__global__ __launch_bounds__(256) void pe_build_kernel(
    const float4* __restrict__ wgt,   // (4096, 256)
    float4* __restrict__ pe_ws)       // (3328, 256)
{
    const int b  = blockIdx.x;
    const int d4 = threadIdx.x;
    float4 pe;
    if (b < 1024) pe = bicubic_pe(wgt, b, 32, d4);
    else          pe = bicubic_pe(wgt, b - 1024, 48, d4);
    pe_ws[(size_t)b * 256 + d4] = pe;
}

// Kernel B: grid-stride streaming add over 12,058,624 float4 elements.
// 1472 blocks x 256 threads x 32 elems/thread == N exactly (no guards).
// rows: [0,8192) g0 t=8 32x32 | [8192,26624) g1 t=8 48x48 |
//       [26624,43008) g2 t=4 64x64 | [43008,47104) g3 t=1 64x64
__global__ __launch_bounds__(256) void posemb_add_kernel(
    const float4* __restrict__ x,     // (47104*256,) float4
    const float4* __restrict__ wgt,   // (4096*256,)
    const float4* __restrict__ tw,    // (16*256,)
    const float4* __restrict__ pe_ws, // (3328*256,)
    float4* __restrict__ out)
{
    const int S = 1472 * 256;                 // total threads = grid stride
    int e0 = blockIdx.x * 256 + threadIdx.x;  // element index (fits int32)

    for (int it = 0; it < 8; ++it) {
        int e[4];
        float4 xv[4];
#pragma unroll
        for (int k = 0; k < 4; ++k) {
            e[k] = e0 + k * S;
            xv[k] = x[e[k]];                  // 4 independent HBM loads in flight
        }
#pragma unroll
        for (int k = 0; k < 4; ++k) {
            const int ee  = e[k];
            const int row = ee >> 8;
            const int d4  = ee & 255;
            float4 pe, tv;
            bool has_tw = true;
            if (row < 8192) {                         // g0: pe table
                pe = pe_ws[ee & 0x3FFFF];             // (row%1024)*256+d4
                tv = tw[((ee >> 18) << 8) | d4];      // f = row>>10
            } else if (row < 26624) {                 // g1: pe table
                const int r  = ee - 8192 * 256;
                const int f  = (unsigned)r / 589824u; // 2304*256, magic-mul
                pe = pe_ws[1024 * 256 + (r - f * 589824)];
                tv = tw[(f << 8) | d4];
            } else if (row < 43008) {                 // g2: direct weight
                const int r = ee - 26624 * 256;
                pe = wgt[r & 0xFFFFF];                // (row%4096)*256+d4
                tv = tw[((r >> 20) << 8) | d4];
            } else {                                  // g3: direct, no time emb
                pe = wgt[ee - 43008 * 256];
                has_tw = false;
                tv = make_float4(0.f, 0.f, 0.f, 0.f);
            }
            float4 o;
            o.x = xv[k].x + pe.x;
            o.y = xv[k].y + pe.y;
            o.z = xv[k].z + pe.z;
            o.w = xv[k].w + pe.w;
            if (has_tw) { o.x += tv.x; o.y += tv.y; o.z += tv.z; o.w += tv.w; }
            nt_store4((float4*)&out[ee], o);
        }
        e0 += 4 * S;
    }
}

// Fallback (R3 structure) if ws is too small for the pe table.
template <int T>
__device__ __forceinline__ void add_frames(const float4* __restrict__ x,
                                           const float4* __restrict__ tw,
                                           float4* __restrict__ out,
                                           size_t rowbase, int ppf, int px, int d4,
                                           float4 pe) {
    const size_t base = (rowbase + (size_t)px) * 256 + d4;
    const size_t fstride = (size_t)ppf * 256;
#pragma unroll
    for (int f = 0; f < T; ++f) {
        const float4 xv = x[base + (size_t)f * fstride];
        float4 tv = make_float4(0.f, 0.f, 0.f, 0.f);
        if (T > 1) tv = tw[(size_t)f * 256 + d4];
        nt_store4(&out[base + (size_t)f * fstride],
                  make_float4(xv.x + pe.x + tv.x, xv.y + pe.y + tv.y,
                              xv.z + pe.z + tv.z, xv.w + pe.w + tv.w));
    }
}

__global__ __launch_bounds__(256) void posemb_fallback_kernel(
    const float4* __restrict__ x, const float4* __restrict__ wgt,
    const float4* __restrict__ tw, float4* __restrict__ out)
{
    const int b  = blockIdx.x;
    const int d4 = threadIdx.x;
    if (b < 1024) {
        const float4 pe = bicubic_pe(wgt, b, 32, d4);
        add_frames<8>(x, tw, out, 0, 1024, b, d4, pe);
    } else if (b < 3328) {
        const int px = b - 1024;
        const float4 pe = bicubic_pe(wgt, px, 48, d4);
        add_frames<8>(x, tw, out, 8192, 2304, px, d4, pe);
    } else if (b < 7424) {
        const int px = b - 3328;
        const float4 pe = wgt[(size_t)px * 256 + d4];
        add_frames<4>(x, tw, out, 26624, 4096, px, d4, pe);
    } else {
        const int px = b - 7424;
        const float4 pe = wgt[(size_t)px * 256 + d4];
        add_frames<1>(x, tw, out, 43008, 4096, px, d4, pe);
    }
}

extern "C" void kernel_launch(void* const* d_in, const int* in_sizes, int n_in,
                              void* d_out, int out_size, void* d_ws, size_t ws_size,
                              hipStream_t stream) {
    const float4* x   = (const float4*)d_in[0];
    const float4* wgt = (const float4*)d_in[1];
    const float4* tw  = (const float4*)d_in[2];
    float4* out = (float4*)d_out;

    const size_t pe_bytes = (size_t)3328 * 256 * sizeof(float4);  // 3.4 MB
    if (ws_size >= pe_bytes) {
        float4* pe_ws = (float4*)d_ws;
        pe_build_kernel<<<3328, 256, 0, stream>>>(wgt, pe_ws);
        posemb_add_kernel<<<1472, 256, 0, stream>>>(x, wgt, tw, pe_ws, out);
    } else {
        posemb_fallback_kernel<<<11520, 256, 0, stream>>>(x, wgt, tw, out);
    }
}

// Round 7
// 76.716 us; speedup vs baseline: 1.1758x; 1.1758x over previous
//
#include <hip/hip_runtime.h>

#define CUBIC_A (-0.75f)

typedef float f4nt __attribute__((ext_vector_type(4)));

__device__ __forceinline__ void nt_store4(float4* p, float4 v) {
    f4nt t;
    t.x = v.x; t.y = v.y; t.z = v.z; t.w = v.w;
    __builtin_nontemporal_store(t, (f4nt*)p);
}

__device__ __forceinline__ float4 add3(float4 a, float4 b, float4 c) {
    return make_float4(a.x + b.x + c.x, a.y + b.y + c.y,
                       a.z + b.z + c.z, a.w + b.w + c.w);
}
__device__ __forceinline__ float4 add2(float4 a, float4 b) {
    return make_float4(a.x + b.x, a.y + b.y, a.z + b.z, a.w + b.w);
}

__device__ __forceinline__ float cubic_w(float d) {
    float ad = fabsf(d);
    if (ad <= 1.0f) return ((CUBIC_A + 2.0f) * ad - (CUBIC_A + 3.0f)) * ad * ad + 1.0f;
    if (ad < 2.0f)  return CUBIC_A * (((ad - 5.0f) * ad + 8.0f) * ad - 4.0f);
    return 0.0f;
}

__device__ __forceinline__ float4 bicubic_pe(const float4* __restrict__ wgt,
                                             int px, int out_hw, int d4) {
    const int i = px / out_hw;
    const int j = px % out_hw;
    const float scale = 64.0f / (float)out_hw;
    const float si = ((float)i + 0.5f) * scale - 0.5f;
    const float sj = ((float)j + 0.5f) * scale - 0.5f;
    const int i0 = (int)floorf(si);
    const int j0 = (int)floorf(sj);
    int ih[4], iw[4];
    float wh[4], ww[4];
#pragma unroll
    for (int a = 0; a < 4; ++a) {
        int tp = i0 - 1 + a;
        wh[a] = cubic_w(si - (float)tp);
        ih[a] = min(63, max(0, tp));
        tp = j0 - 1 + a;
        ww[a] = cubic_w(sj - (float)tp);
        iw[a] = min(63, max(0, tp));
    }
    float ax = 0.f, ay = 0.f, az = 0.f, aw = 0.f;
#pragma unroll
    for (int a = 0; a < 4; ++a) {
        float rx = 0.f, ry = 0.f, rz = 0.f, rw = 0.f;
#pragma unroll
        for (int c = 0; c < 4; ++c) {
            const float4 v = wgt[(size_t)(ih[a] * 64 + iw[c]) * 256 + d4];
            rx = fmaf(ww[c], v.x, rx);
            ry = fmaf(ww[c], v.y, ry);
            rz = fmaf(ww[c], v.z, rz);
            rw = fmaf(ww[c], v.w, rw);
        }
        ax = fmaf(wh[a], rx, ax);
        ay = fmaf(wh[a], ry, ay);
        az = fmaf(wh[a], rz, az);
        aw = fmaf(wh[a], rw, aw);
    }
    return make_float4(ax, ay, az, aw);
}

// GRIDS = [(8,32,32),(8,48,48),(4,64,64),(1,64,64)]; dim=1024 (256 float4).
// 512-thread blocks: tid = fh*256 + d4; fh in {0,1} is the frame-half.
// Each block owns ONE pixel (pe computed/loaded once); frame-half fh handles
// frames {fh, fh+2, fh+4, fh+6} -> serial depth t/2. x-loads issued FIRST so
// their HBM latency hides under the bicubic tap compute.
// blocks: [0,1024) g0 | [1024,3328) g1 | [3328,7424) g2 | [7424,9472) g3(2px/blk)
__global__ __launch_bounds__(512) void posemb_kernel(
    const float4* __restrict__ x,     // (47104, 256)
    const float4* __restrict__ wgt,   // (4096, 256)
    const float4* __restrict__ tw,    // (16, 256)
    float4* __restrict__ out)         // (47104, 256)
{
    const int b   = blockIdx.x;
    const int tid = threadIdx.x;
    const int d4  = tid & 255;
    const int fh  = tid >> 8;   // 0 or 1

    if (b < 1024) {                            // g0: t=8, 32x32, interp
        const int px = b;
        const size_t base = ((size_t)(fh * 1024 + px)) * 256 + d4;   // row = fh*1024+px
        const size_t st   = (size_t)2048 * 256;                       // 2 frames
        const float4 xv0 = x[base];
        const float4 xv1 = x[base + st];
        const float4 xv2 = x[base + 2 * st];
        const float4 xv3 = x[base + 3 * st];
        const float4 tv0 = tw[(size_t)(fh    ) * 256 + d4];
        const float4 tv1 = tw[(size_t)(fh + 2) * 256 + d4];
        const float4 tv2 = tw[(size_t)(fh + 4) * 256 + d4];
        const float4 tv3 = tw[(size_t)(fh + 6) * 256 + d4];
        const float4 pe = bicubic_pe(wgt, px, 32, d4);
        nt_store4(&out[base],          add3(xv0, pe, tv0));
        nt_store4(&out[base + st],     add3(xv1, pe, tv1));
        nt_store4(&out[base + 2 * st], add3(xv2, pe, tv2));
        nt_store4(&out[base + 3 * st], add3(xv3, pe, tv3));
    } else if (b < 3328) {                     // g1: t=8, 48x48, interp
        const int px = b - 1024;
        const size_t base = ((size_t)(8192 + fh * 2304 + px)) * 256 + d4;
        const size_t st   = (size_t)2 * 2304 * 256;
        const float4 xv0 = x[base];
        const float4 xv1 = x[base + st];
        const float4 xv2 = x[base + 2 * st];
        const float4 xv3 = x[base + 3 * st];
        const float4 tv0 = tw[(size_t)(fh    ) * 256 + d4];
        const float4 tv1 = tw[(size_t)(fh + 2) * 256 + d4];
        const float4 tv2 = tw[(size_t)(fh + 4) * 256 + d4];
        const float4 tv3 = tw[(size_t)(fh + 6) * 256 + d4];
        const float4 pe = bicubic_pe(wgt, px, 48, d4);
        nt_store4(&out[base],          add3(xv0, pe, tv0));
        nt_store4(&out[base + st],     add3(xv1, pe, tv1));
        nt_store4(&out[base + 2 * st], add3(xv2, pe, tv2));
        nt_store4(&out[base + 3 * st], add3(xv3, pe, tv3));
    } else if (b < 7424) {                     // g2: t=4, 64x64, direct
        const int px = b - 3328;
        const size_t base = ((size_t)(26624 + fh * 4096 + px)) * 256 + d4;
        const size_t st   = (size_t)2 * 4096 * 256;
        const float4 xv0 = x[base];
        const float4 xv1 = x[base + st];
        const float4 pe  = wgt[(size_t)px * 256 + d4];
        const float4 tv0 = tw[(size_t)(fh    ) * 256 + d4];
        const float4 tv1 = tw[(size_t)(fh + 2) * 256 + d4];
        nt_store4(&out[base],      add3(xv0, pe, tv0));
        nt_store4(&out[base + st], add3(xv1, pe, tv1));
    } else {                                   // g3: t=1, 64x64, direct; 2 px/block
        const int px = 2 * (b - 7424) + fh;
        const size_t e = ((size_t)(43008 + px)) * 256 + d4;
        const float4 xv = x[e];
        const float4 pe = wgt[(size_t)px * 256 + d4];
        nt_store4(&out[e], add2(xv, pe));
    }
}

extern "C" void kernel_launch(void* const* d_in, const int* in_sizes, int n_in,
                              void* d_out, int out_size, void* d_ws, size_t ws_size,
                              hipStream_t stream) {
    const float4* x   = (const float4*)d_in[0];
    const float4* wgt = (const float4*)d_in[1];
    const float4* tw  = (const float4*)d_in[2];
    float4* out = (float4*)d_out;
    // 1024 + 2304 + 4096 + 2048 = 9472 blocks x 512 threads
    posemb_kernel<<<9472, 512, 0, stream>>>(x, wgt, tw, out);
}